// Round 8
// baseline (860.283 us; speedup 1.0000x reference)
//
#include <hip/hip_runtime.h>
#include <hip/hip_bf16.h>
#include <cstdint>
#include <cstddef>

#define NI 8192
#define NC 8192
#define RV 7
#define DD 256

typedef __bf16  bf16x8 __attribute__((ext_vector_type(8)));
typedef float   f32x4  __attribute__((ext_vector_type(4)));
typedef __fp16  f16x2  __attribute__((ext_vector_type(2)));

// ws layout:
//   imgs: per img-block ib (16) x chunk t=r*8+j (56): [4 u][512 row] x 16B = 32KB
//   caps: per cap-block cb (64): 8 chunks x [4 u][128 row] x 16B = 64KB
#define IMGS_WS_BYTES (16u * 56u * 32768u)   /* 29,360,128 */
#define CAPS_WS_OFF   IMGS_WS_BYTES
#define CAPS_WS_BYTES (64u * 65536u)         /* 4,194,304 */
#define WS_NEEDED     ((size_t)(IMGS_WS_BYTES + CAPS_WS_BYTES))

static __device__ __forceinline__ unsigned pkbf(float x, float y) {
  unsigned a = __float_as_uint(x) + 0x8000u;
  unsigned b = __float_as_uint(y) + 0x8000u;
  return __builtin_amdgcn_perm(b, a, 0x07060302u);
}

static __device__ __forceinline__ void gload16(const void* g, void* l) {
  __builtin_amdgcn_global_load_lds(
      (const __attribute__((address_space(1))) void*)g,
      (__attribute__((address_space(3))) void*)l, 16, 0, 0);
}

// ---------------- conversion pre-passes (f32 -> bf16, tile-image layout) ---
__global__ __launch_bounds__(256)
void conv_imgs(const float* __restrict__ imgs, uint4* __restrict__ ws) {
  unsigned T = blockIdx.x * 256u + threadIdx.x;   // 0..1,835,007
  unsigned img = T / 224u;                        // 8192 imgs x 224 units
  unsigned rem = T - img * 224u;
  unsigned r  = rem >> 5;                         // view 0..6
  unsigned ju = rem & 31u;                        // k-unit 0..31 (k = ju*8)
  const float* s = imgs + ((size_t)img * RV + r) * DD + ju * 8u;
  float4 a = *(const float4*)s;
  float4 b = *(const float4*)(s + 4);
  uint4 v = { pkbf(a.x, a.y), pkbf(a.z, a.w), pkbf(b.x, b.y), pkbf(b.z, b.w) };
  unsigned ib = img >> 9, lrow = img & 511u;
  unsigned j = ju >> 2, u = ju & 3u;
  unsigned t = r * 8u + j;
  unsigned byteoff = (ib * 56u + t) * 32768u + u * 8192u + lrow * 16u;
  ws[byteoff >> 4] = v;
}

__global__ __launch_bounds__(256)
void conv_caps(const float* __restrict__ caps, uint4* __restrict__ ws) {
  unsigned T = blockIdx.x * 256u + threadIdx.x;   // 0..262,143
  unsigned gr = T >> 5;                           // cap row 0..8191
  unsigned ju = T & 31u;                          // k-unit 0..31
  const float* s = caps + (size_t)gr * DD + ju * 8u;
  float4 a = *(const float4*)s;
  float4 b = *(const float4*)(s + 4);
  uint4 v = { pkbf(a.x, a.y), pkbf(a.z, a.w), pkbf(b.x, b.y), pkbf(b.z, b.w) };
  unsigned cb = gr >> 7, row = gr & 127u;
  unsigned j = ju >> 2, u = ju & 3u;
  unsigned byteoff = cb * 65536u + j * 8192u + u * 2048u + row * 16u;
  ws[byteoff >> 4] = v;
}

// ---------------- main GEMM+max kernel ------------------------------------
// block tile 512 imgs x 128 caps; 8 waves (4m x 2n), wave tile 128x64.
// B resident in LDS (64KB, one prologue barrier). A fragments loaded
// global->VGPR directly (L2-resident panel) in a register ping-pong:
// p0-3 reloaded for chunk t+1 right after their last MFMA use in chunk t,
// p4-7 likewise. NO barriers / NO LDS traffic for A in the main loop —
// waves drift freely and loads of one wave overlap MFMA of its SIMD sibling.
__global__ __launch_bounds__(512, 2)
void mvm_mfma(const char* __restrict__ wi, const char* __restrict__ wcap,
              float* __restrict__ out)
{
  __shared__ __align__(1024) char ldsB[65536];   // caps panel, full K

  const int tid  = threadIdx.x;
  const int lane = tid & 63;
  const int wid  = tid >> 6;
  const int wm   = wid >> 1;   // 0..3 : m-strip of 128
  const int wn   = wid & 1;    // 0..1 : n-strip of 64

  const int bid = (int)blockIdx.x;                 // 1024 blocks
  const int swz = (bid & 7) * 128 + (bid >> 3);    // bijective XCD swizzle
  const int ib  = swz >> 6;    // 0..15 : 2 A panels per XCD -> L2-resident
  const int cb  = swz & 63;    // 0..63

  const char* abase = wi   + (size_t)ib * (56u * 32768u);
  const char* bbase = wcap + (size_t)cb * 65536u;

  // prologue: stage B panel to LDS (only barrier in the kernel)
  #pragma unroll
  for (int l = 0; l < 8; ++l)
    gload16(bbase + l * 8192 + tid * 16, ldsB + l * 8192 + wid * 1024);
  asm volatile("s_waitcnt vmcnt(0)" ::: "memory");
  __builtin_amdgcn_s_barrier();
  asm volatile("" ::: "memory");

  const int lrow = lane & 15;
  const int lu   = lane >> 4;
  // per-lane A pointer: chunk-image [4 u][512 row] x 16B
  const char* ap = abase + lu * 8192 + (wm * 128 + lrow) * 16;
  const char* const bB = ldsB + lu * 2048 + (wn * 64 + lrow) * 16;

  // register A fragments for current chunk (half-chunk ping-pong reload)
  bf16x8 p0 = *(const bf16x8*)(ap + 0 * 256);
  bf16x8 p1 = *(const bf16x8*)(ap + 1 * 256);
  bf16x8 p2 = *(const bf16x8*)(ap + 2 * 256);
  bf16x8 p3 = *(const bf16x8*)(ap + 3 * 256);
  bf16x8 p4 = *(const bf16x8*)(ap + 4 * 256);
  bf16x8 p5 = *(const bf16x8*)(ap + 5 * 256);
  bf16x8 p6 = *(const bf16x8*)(ap + 6 * 256);
  bf16x8 p7 = *(const bf16x8*)(ap + 7 * 256);
  ap += 32768;

  f16x2 om[8][4][2];
  #pragma unroll
  for (int m = 0; m < 8; ++m)
    #pragma unroll
    for (int n = 0; n < 4; ++n)
      #pragma unroll
      for (int h = 0; h < 2; ++h)
        om[m][n][h] = (f16x2){(__fp16)-65504.f, (__fp16)-65504.f};

  f32x4 acc[8][4];

  #pragma unroll 1
  for (int r = 0; r < RV; ++r) {
    #pragma unroll
    for (int m = 0; m < 8; ++m)
      #pragma unroll
      for (int n = 0; n < 4; ++n)
        acc[m][n] = (f32x4){0.f, 0.f, 0.f, 0.f};

    #pragma unroll
    for (int j = 0; j < 8; ++j) {
      // B fragments for this chunk (16-bit ds imm offsets, zero addr VALU)
      bf16x8 b0 = *(const bf16x8*)(bB + j * 8192 + 0 * 256);
      bf16x8 b1 = *(const bf16x8*)(bB + j * 8192 + 1 * 256);
      bf16x8 b2 = *(const bf16x8*)(bB + j * 8192 + 2 * 256);
      bf16x8 b3 = *(const bf16x8*)(bB + j * 8192 + 3 * 256);

      // cluster 1: m0-3 (consumes p0-3)
      acc[0][0] = __builtin_amdgcn_mfma_f32_16x16x32_bf16(p0, b0, acc[0][0], 0, 0, 0);
      acc[1][0] = __builtin_amdgcn_mfma_f32_16x16x32_bf16(p1, b0, acc[1][0], 0, 0, 0);
      acc[2][0] = __builtin_amdgcn_mfma_f32_16x16x32_bf16(p2, b0, acc[2][0], 0, 0, 0);
      acc[3][0] = __builtin_amdgcn_mfma_f32_16x16x32_bf16(p3, b0, acc[3][0], 0, 0, 0);
      acc[0][1] = __builtin_amdgcn_mfma_f32_16x16x32_bf16(p0, b1, acc[0][1], 0, 0, 0);
      acc[1][1] = __builtin_amdgcn_mfma_f32_16x16x32_bf16(p1, b1, acc[1][1], 0, 0, 0);
      acc[2][1] = __builtin_amdgcn_mfma_f32_16x16x32_bf16(p2, b1, acc[2][1], 0, 0, 0);
      acc[3][1] = __builtin_amdgcn_mfma_f32_16x16x32_bf16(p3, b1, acc[3][1], 0, 0, 0);
      acc[0][2] = __builtin_amdgcn_mfma_f32_16x16x32_bf16(p0, b2, acc[0][2], 0, 0, 0);
      acc[1][2] = __builtin_amdgcn_mfma_f32_16x16x32_bf16(p1, b2, acc[1][2], 0, 0, 0);
      acc[2][2] = __builtin_amdgcn_mfma_f32_16x16x32_bf16(p2, b2, acc[2][2], 0, 0, 0);
      acc[3][2] = __builtin_amdgcn_mfma_f32_16x16x32_bf16(p3, b2, acc[3][2], 0, 0, 0);
      acc[0][3] = __builtin_amdgcn_mfma_f32_16x16x32_bf16(p0, b3, acc[0][3], 0, 0, 0);
      acc[1][3] = __builtin_amdgcn_mfma_f32_16x16x32_bf16(p1, b3, acc[1][3], 0, 0, 0);
      acc[2][3] = __builtin_amdgcn_mfma_f32_16x16x32_bf16(p2, b3, acc[2][3], 0, 0, 0);
      acc[3][3] = __builtin_amdgcn_mfma_f32_16x16x32_bf16(p3, b3, acc[3][3], 0, 0, 0);

      // reload p0-3 with chunk t+1 (WAR on the 16 MFMAs above orders this)
      p0 = *(const bf16x8*)(ap + 0 * 256);
      p1 = *(const bf16x8*)(ap + 1 * 256);
      p2 = *(const bf16x8*)(ap + 2 * 256);
      p3 = *(const bf16x8*)(ap + 3 * 256);

      // cluster 2: m4-7 (consumes p4-7)
      acc[4][0] = __builtin_amdgcn_mfma_f32_16x16x32_bf16(p4, b0, acc[4][0], 0, 0, 0);
      acc[5][0] = __builtin_amdgcn_mfma_f32_16x16x32_bf16(p5, b0, acc[5][0], 0, 0, 0);
      acc[6][0] = __builtin_amdgcn_mfma_f32_16x16x32_bf16(p6, b0, acc[6][0], 0, 0, 0);
      acc[7][0] = __builtin_amdgcn_mfma_f32_16x16x32_bf16(p7, b0, acc[7][0], 0, 0, 0);
      acc[4][1] = __builtin_amdgcn_mfma_f32_16x16x32_bf16(p4, b1, acc[4][1], 0, 0, 0);
      acc[5][1] = __builtin_amdgcn_mfma_f32_16x16x32_bf16(p5, b1, acc[5][1], 0, 0, 0);
      acc[6][1] = __builtin_amdgcn_mfma_f32_16x16x32_bf16(p6, b1, acc[6][1], 0, 0, 0);
      acc[7][1] = __builtin_amdgcn_mfma_f32_16x16x32_bf16(p7, b1, acc[7][1], 0, 0, 0);
      acc[4][2] = __builtin_amdgcn_mfma_f32_16x16x32_bf16(p4, b2, acc[4][2], 0, 0, 0);
      acc[5][2] = __builtin_amdgcn_mfma_f32_16x16x32_bf16(p5, b2, acc[5][2], 0, 0, 0);
      acc[6][2] = __builtin_amdgcn_mfma_f32_16x16x32_bf16(p6, b2, acc[6][2], 0, 0, 0);
      acc[7][2] = __builtin_amdgcn_mfma_f32_16x16x32_bf16(p7, b2, acc[7][2], 0, 0, 0);
      acc[4][3] = __builtin_amdgcn_mfma_f32_16x16x32_bf16(p4, b3, acc[4][3], 0, 0, 0);
      acc[5][3] = __builtin_amdgcn_mfma_f32_16x16x32_bf16(p5, b3, acc[5][3], 0, 0, 0);
      acc[6][3] = __builtin_amdgcn_mfma_f32_16x16x32_bf16(p6, b3, acc[6][3], 0, 0, 0);
      acc[7][3] = __builtin_amdgcn_mfma_f32_16x16x32_bf16(p7, b3, acc[7][3], 0, 0, 0);

      // reload p4-7 with chunk t+1
      p4 = *(const bf16x8*)(ap + 4 * 256);
      p5 = *(const bf16x8*)(ap + 5 * 256);
      p6 = *(const bf16x8*)(ap + 6 * 256);
      p7 = *(const bf16x8*)(ap + 7 * 256);
      ap += 32768;
      // (final j of final r loads chunk 56 = start of caps region: in-bounds,
      //  never consumed)
    }

    // fold view into running max (packed f16)
    #pragma unroll
    for (int m = 0; m < 8; ++m)
      #pragma unroll
      for (int n = 0; n < 4; ++n) {
        f16x2 lo = __builtin_amdgcn_cvt_pkrtz(acc[m][n][0], acc[m][n][1]);
        f16x2 hi = __builtin_amdgcn_cvt_pkrtz(acc[m][n][2], acc[m][n][3]);
        om[m][n][0] = __builtin_elementwise_max(om[m][n][0], lo);
        om[m][n][1] = __builtin_elementwise_max(om[m][n][1], hi);
      }
  }

  // epilogue: unpack f16 -> f32 and store
  const int rbase = ib * 512 + wm * 128;
  const int cbase = cb * 128 + wn * 64;
  #pragma unroll
  for (int m = 0; m < 8; ++m)
    #pragma unroll
    for (int h = 0; h < 2; ++h)
      #pragma unroll
      for (int e = 0; e < 2; ++e) {
        size_t ro = (size_t)(rbase + m * 16 + lu * 4 + h * 2 + e) * NC + cbase + lrow;
        #pragma unroll
        for (int n = 0; n < 4; ++n)
          out[ro + n * 16] = (float)om[m][n][h][e];
      }
}

// ---------------- fallback (no-ws path) ------------------------------------
__global__ __launch_bounds__(512, 1)
void mvm_fallback(const float* __restrict__ imgs, const float* __restrict__ caps,
                  float* __restrict__ out)
{
  __shared__ __align__(16) char ldsB[128 * 512];
  __shared__ __align__(16) char ldsA[2][256 * 128];

  const int tid  = threadIdx.x;
  const int lane = tid & 63;
  const int wid  = tid >> 6;
  const int wr   = wid >> 1;
  const int wc   = wid & 1;
  const int i0   = blockIdx.y * 256;
  const int c0   = blockIdx.x * 128;

  #pragma unroll
  for (int it = 0; it < 8; ++it) {
    int c    = tid + it * 512;
    int row  = c >> 5;
    int colb = (c & 31) * 16;
    const float* p = caps + (size_t)(c0 + row) * DD + (c & 31) * 8;
    float4 a = *(const float4*)p;
    float4 b = *(const float4*)(p + 4);
    uint4 v;
    v.x = pkbf(a.x, a.y); v.y = pkbf(a.z, a.w);
    v.z = pkbf(b.x, b.y); v.w = pkbf(b.z, b.w);
    *(uint4*)(ldsB + row * 512 + (colb ^ ((row & 7) << 4))) = v;
  }
  #pragma unroll
  for (int it = 0; it < 4; ++it) {
    int c    = tid + it * 512;
    int row  = c >> 3;
    int colb = (c & 7) * 16;
    const float* p = imgs + ((size_t)(i0 + row) * RV + 0) * DD + (c & 7) * 8;
    float4 a = *(const float4*)p;
    float4 b = *(const float4*)(p + 4);
    uint4 v;
    v.x = pkbf(a.x, a.y); v.y = pkbf(a.z, a.w);
    v.z = pkbf(b.x, b.y); v.w = pkbf(b.z, b.w);
    *(uint4*)(ldsA[0] + row * 128 + (colb ^ ((row & 7) << 4))) = v;
  }
  __syncthreads();

  f32x4 omax[4][4];
  #pragma unroll
  for (int m = 0; m < 4; ++m)
    #pragma unroll
    for (int n = 0; n < 4; ++n)
      #pragma unroll
      for (int j = 0; j < 4; ++j)
        omax[m][n][j] = -3.4e38f;

  f32x4 acc[4][4];
  int cur = 0;
  const int lrow = lane & 15;
  const int lkb  = (lane >> 4) * 16;

  for (int ch = 0; ch < RV * 4; ++ch) {
    const int kc = ch & 3;
    if (kc == 0) {
      #pragma unroll
      for (int m = 0; m < 4; ++m)
        #pragma unroll
        for (int n = 0; n < 4; ++n)
          acc[m][n] = (f32x4){0.f, 0.f, 0.f, 0.f};
    }
    const int  chn  = ch + 1;
    const bool hasn = (chn < RV * 4);
    float4 pf[8];
    if (hasn) {
      const int rn = chn >> 2;
      const int kn = (chn & 3) * 64;
      #pragma unroll
      for (int it = 0; it < 4; ++it) {
        int c   = tid + it * 512;
        int row = c >> 3;
        const float* p = imgs + ((size_t)(i0 + row) * RV + rn) * DD + kn + (c & 7) * 8;
        pf[2 * it]     = *(const float4*)p;
        pf[2 * it + 1] = *(const float4*)(p + 4);
      }
    }
    #pragma unroll
    for (int ks = 0; ks < 2; ++ks) {
      bf16x8 af[4], bfr[4];
      #pragma unroll
      for (int m = 0; m < 4; ++m) {
        int row = wr * 64 + m * 16 + lrow;
        af[m] = *(const bf16x8*)(ldsA[cur] + row * 128 + ((ks * 64 + lkb) ^ ((row & 7) << 4)));
      }
      #pragma unroll
      for (int n = 0; n < 4; ++n) {
        int row = wc * 64 + n * 16 + lrow;
        bfr[n] = *(const bf16x8*)(ldsB + row * 512 + (((ch & 3) * 128 + ks * 64 + lkb) ^ ((row & 7) << 4)));
      }
      #pragma unroll
      for (int m = 0; m < 4; ++m)
        #pragma unroll
        for (int n = 0; n < 4; ++n)
          acc[m][n] = __builtin_amdgcn_mfma_f32_16x16x32_bf16(af[m], bfr[n], acc[m][n], 0, 0, 0);
    }
    if (hasn) {
      #pragma unroll
      for (int it = 0; it < 4; ++it) {
        int c    = tid + it * 512;
        int row  = c >> 3;
        int colb = (c & 7) * 16;
        uint4 v;
        v.x = pkbf(pf[2 * it].x,     pf[2 * it].y);
        v.y = pkbf(pf[2 * it].z,     pf[2 * it].w);
        v.z = pkbf(pf[2 * it + 1].x, pf[2 * it + 1].y);
        v.w = pkbf(pf[2 * it + 1].z, pf[2 * it + 1].w);
        *(uint4*)(ldsA[cur ^ 1] + row * 128 + (colb ^ ((row & 7) << 4))) = v;
      }
    }
    __syncthreads();
    cur ^= 1;
    if (kc == 3) {
      #pragma unroll
      for (int m = 0; m < 4; ++m)
        #pragma unroll
        for (int n = 0; n < 4; ++n)
          #pragma unroll
          for (int j = 0; j < 4; ++j)
            omax[m][n][j] = fmaxf(omax[m][n][j], acc[m][n][j]);
    }
  }

  const int rbase = i0 + wr * 64;
  const int cbase = c0 + wc * 64;
  const int lr4   = (lane >> 4) * 4;
  const int lc    = lane & 15;
  #pragma unroll
  for (int m = 0; m < 4; ++m)
    #pragma unroll
    for (int j = 0; j < 4; ++j) {
      size_t ro = (size_t)(rbase + m * 16 + lr4 + j) * NC;
      #pragma unroll
      for (int n = 0; n < 4; ++n)
        out[ro + cbase + n * 16 + lc] = omax[m][n][j];
    }
}

extern "C" void kernel_launch(void* const* d_in, const int* in_sizes, int n_in,
                              void* d_out, int out_size, void* d_ws, size_t ws_size,
                              hipStream_t stream) {
  const float* imgs = (const float*)d_in[0];
  const float* caps = (const float*)d_in[1];
  float* out = (float*)d_out;

  if (ws_size >= WS_NEEDED) {
    char* ws = (char*)d_ws;
    conv_imgs<<<7168, 256, 0, stream>>>(imgs, (uint4*)ws);
    conv_caps<<<1024, 256, 0, stream>>>(caps, (uint4*)(ws + CAPS_WS_OFF));
    mvm_mfma<<<1024, 512, 0, stream>>>((const char*)ws, (const char*)(ws + CAPS_WS_OFF), out);
  } else {
    dim3 grid(NC / 128, NI / 256);
    mvm_fallback<<<grid, 512, 0, stream>>>(imgs, caps, out);
  }
}

// Round 10
// 338.447 us; speedup vs baseline: 2.5419x; 2.5419x over previous
//
#include <hip/hip_runtime.h>
#include <hip/hip_bf16.h>
#include <cstdint>
#include <cstddef>

#define NI 8192
#define NC 8192
#define RV 7
#define DD 256

typedef __bf16  bf16x8 __attribute__((ext_vector_type(8)));
typedef float   f32x4  __attribute__((ext_vector_type(4)));
typedef __fp16  f16x2  __attribute__((ext_vector_type(2)));

// ws layout:
//   imgs: per img-block ib (32) x chunk t=r*8+j (56): [4 u][256 row] x 16B = 16KB
//   caps: per cap-block cb (64): [8 j][4 u][128 row] x 16B = 64KB
#define IMGS_WS_BYTES (32u * 56u * 16384u)   /* 29,360,128 */
#define CAPS_WS_OFF   IMGS_WS_BYTES
#define CAPS_WS_BYTES (64u * 65536u)         /* 4,194,304 */
#define WS_NEEDED     ((size_t)(IMGS_WS_BYTES + CAPS_WS_BYTES))

static __device__ __forceinline__ unsigned pkbf(float x, float y) {
  unsigned a = __float_as_uint(x) + 0x8000u;
  unsigned b = __float_as_uint(y) + 0x8000u;
  return __builtin_amdgcn_perm(b, a, 0x07060302u);
}

static __device__ __forceinline__ void gload16(const void* g, void* l) {
  __builtin_amdgcn_global_load_lds(
      (const __attribute__((address_space(1))) void*)g,
      (__attribute__((address_space(3))) void*)l, 16, 0, 0);
}

// ---------------- conversion pre-passes (f32 -> bf16, tile-image layout) ---
__global__ __launch_bounds__(256)
void conv_imgs(const float* __restrict__ imgs, uint4* __restrict__ ws) {
  unsigned T = blockIdx.x * 256u + threadIdx.x;   // 0..1,835,007
  unsigned img = T / 224u;                        // 8192 imgs x 224 units
  unsigned rem = T - img * 224u;
  unsigned r  = rem >> 5;                         // view 0..6
  unsigned ju = rem & 31u;                        // k-unit 0..31 (k = ju*8)
  const float* s = imgs + ((size_t)img * RV + r) * DD + ju * 8u;
  float4 a = *(const float4*)s;
  float4 b = *(const float4*)(s + 4);
  uint4 v = { pkbf(a.x, a.y), pkbf(a.z, a.w), pkbf(b.x, b.y), pkbf(b.z, b.w) };
  unsigned ib = img >> 8, lrow = img & 255u;
  unsigned j = ju >> 2, u = ju & 3u;
  unsigned t = r * 8u + j;
  unsigned byteoff = (ib * 56u + t) * 16384u + u * 4096u + lrow * 16u;
  ws[byteoff >> 4] = v;
}

__global__ __launch_bounds__(256)
void conv_caps(const float* __restrict__ caps, uint4* __restrict__ ws) {
  unsigned T = blockIdx.x * 256u + threadIdx.x;   // 0..262,143
  unsigned gr = T >> 5;                           // cap row 0..8191
  unsigned ju = T & 31u;                          // k-unit 0..31
  const float* s = caps + (size_t)gr * DD + ju * 8u;
  float4 a = *(const float4*)s;
  float4 b = *(const float4*)(s + 4);
  uint4 v = { pkbf(a.x, a.y), pkbf(a.z, a.w), pkbf(b.x, b.y), pkbf(b.z, b.w) };
  unsigned cb = gr >> 7, row = gr & 127u;         // 64 panels x 128 rows
  unsigned j = ju >> 2, u = ju & 3u;
  // panel 64KB: [8 j][4 u][128 row] x 16B  (strides 8192 / 2048 / 16)
  unsigned byteoff = cb * 65536u + j * 8192u + u * 2048u + row * 16u;
  ws[byteoff >> 4] = v;
}

// ---------------- main GEMM+max kernel ------------------------------------
// block tile 256 imgs x 128 caps; 4 waves (2m x 2n), wave tile 128x64.
// LDS = B resident 64KB + A chunk single-buffer 16KB = 80KB -> 2 blocks/CU.
// The two co-resident blocks have independent barriers: one block's stage
// drain hides under the other's MFMA (inter-block overlap, m114/T5 regime).
// Per-chunk sync (provably correct, vmcnt BEFORE barrier):
//   reads -> lgkmcnt(0) -> barrier -> stage t+1 -> MFMA -> vmcnt(0) -> barrier
__global__ __launch_bounds__(256, 2)
void mvm_mfma(const char* __restrict__ wi, const char* __restrict__ wcap,
              float* __restrict__ out)
{
  __shared__ __align__(1024) char lds[81920];
  char* const ldsB = lds;            // 64KB caps (full K, [8 j][4 u][128 row])
  char* const ldsA = lds + 65536;    // 16KB imgs chunk (single buffer)

  const int tid  = threadIdx.x;
  const int lane = tid & 63;
  const int wid  = tid >> 6;   // 0..3
  const int wm   = wid >> 1;   // 0..1 : m-strip of 128
  const int wn   = wid & 1;    // 0..1 : n-strip of 64

  const int bid = (int)blockIdx.x;                 // 2048 blocks
  const int swz = (bid & 7) * 256 + (bid >> 3);    // bijective XCD swizzle
  const int ib  = swz >> 6;    // 0..31 : one A panel per XCD-resident group
  const int cb  = swz & 63;    // 0..63

  const char* abase = wi   + (size_t)ib * (56u * 16384u);
  const char* bbase = wcap + (size_t)cb * 65536u;

  // prologue: stage all of B (16 gloads of 4KB) + A chunk 0 (4 gloads)
  #pragma unroll
  for (int l = 0; l < 16; ++l)
    gload16(bbase + l * 4096 + tid * 16, ldsB + l * 4096 + wid * 1024);
  #pragma unroll
  for (int l = 0; l < 4; ++l)
    gload16(abase + l * 4096 + tid * 16, ldsA + l * 4096 + wid * 1024);
  asm volatile("s_waitcnt vmcnt(0)" ::: "memory");
  __builtin_amdgcn_s_barrier();
  asm volatile("" ::: "memory");

  const int lrow = lane & 15;
  const int lu   = lane >> 4;
  const char* const aB = ldsA + lu * 4096 + (wm * 128 + lrow) * 16;
  const char* const bB = ldsB + lu * 2048 + (wn * 64 + lrow) * 16;
  const char* ap = abase + 16384 + tid * 16;   // next chunk to stage = 1

  f16x2 om[8][4][2];
  #pragma unroll
  for (int m = 0; m < 8; ++m)
    #pragma unroll
    for (int n = 0; n < 4; ++n)
      #pragma unroll
      for (int h = 0; h < 2; ++h)
        om[m][n][h] = (f16x2){(__fp16)-65504.f, (__fp16)-65504.f};

  f32x4 acc[8][4];

  #pragma unroll 1
  for (int r = 0; r < RV; ++r) {
    #pragma unroll
    for (int m = 0; m < 8; ++m)
      #pragma unroll
      for (int n = 0; n < 4; ++n)
        acc[m][n] = (f32x4){0.f, 0.f, 0.f, 0.f};

    #pragma unroll
    for (int j = 0; j < 8; ++j) {
      // ---- fragment reads (bank-conflict-free unit-major layout) ----
      bf16x8 b0 = *(const bf16x8*)(bB + j * 8192 + 0 * 256);
      bf16x8 b1 = *(const bf16x8*)(bB + j * 8192 + 1 * 256);
      bf16x8 b2 = *(const bf16x8*)(bB + j * 8192 + 2 * 256);
      bf16x8 b3 = *(const bf16x8*)(bB + j * 8192 + 3 * 256);
      bf16x8 a0 = *(const bf16x8*)(aB + 0 * 256);
      bf16x8 a1 = *(const bf16x8*)(aB + 1 * 256);
      bf16x8 a2 = *(const bf16x8*)(aB + 2 * 256);
      bf16x8 a3 = *(const bf16x8*)(aB + 3 * 256);
      bf16x8 a4 = *(const bf16x8*)(aB + 4 * 256);
      bf16x8 a5 = *(const bf16x8*)(aB + 5 * 256);
      bf16x8 a6 = *(const bf16x8*)(aB + 6 * 256);
      bf16x8 a7 = *(const bf16x8*)(aB + 7 * 256);

      // my reads complete, then signal buffer-free to the block
      asm volatile("s_waitcnt lgkmcnt(0)" ::: "memory");
      __builtin_amdgcn_s_barrier();
      asm volatile("" ::: "memory");

      // ---- stage chunk t+1 into the (now-free) single buffer ----
      if (j < 7 || r < RV - 1) {
        gload16(ap + 0 * 4096, ldsA + 0 * 4096 + wid * 1024);
        gload16(ap + 1 * 4096, ldsA + 1 * 4096 + wid * 1024);
        gload16(ap + 2 * 4096, ldsA + 2 * 4096 + wid * 1024);
        gload16(ap + 3 * 4096, ldsA + 3 * 4096 + wid * 1024);
        ap += 16384;
      }
      __builtin_amdgcn_sched_barrier(0);   // keep stage issue ahead of MFMA

      // ---- 32 MFMA on registers (hides the stage flight time) ----
      __builtin_amdgcn_s_setprio(1);
      acc[0][0] = __builtin_amdgcn_mfma_f32_16x16x32_bf16(a0, b0, acc[0][0], 0, 0, 0);
      acc[1][0] = __builtin_amdgcn_mfma_f32_16x16x32_bf16(a1, b0, acc[1][0], 0, 0, 0);
      acc[2][0] = __builtin_amdgcn_mfma_f32_16x16x32_bf16(a2, b0, acc[2][0], 0, 0, 0);
      acc[3][0] = __builtin_amdgcn_mfma_f32_16x16x32_bf16(a3, b0, acc[3][0], 0, 0, 0);
      acc[4][0] = __builtin_amdgcn_mfma_f32_16x16x32_bf16(a4, b0, acc[4][0], 0, 0, 0);
      acc[5][0] = __builtin_amdgcn_mfma_f32_16x16x32_bf16(a5, b0, acc[5][0], 0, 0, 0);
      acc[6][0] = __builtin_amdgcn_mfma_f32_16x16x32_bf16(a6, b0, acc[6][0], 0, 0, 0);
      acc[7][0] = __builtin_amdgcn_mfma_f32_16x16x32_bf16(a7, b0, acc[7][0], 0, 0, 0);
      acc[0][1] = __builtin_amdgcn_mfma_f32_16x16x32_bf16(a0, b1, acc[0][1], 0, 0, 0);
      acc[1][1] = __builtin_amdgcn_mfma_f32_16x16x32_bf16(a1, b1, acc[1][1], 0, 0, 0);
      acc[2][1] = __builtin_amdgcn_mfma_f32_16x16x32_bf16(a2, b1, acc[2][1], 0, 0, 0);
      acc[3][1] = __builtin_amdgcn_mfma_f32_16x16x32_bf16(a3, b1, acc[3][1], 0, 0, 0);
      acc[4][1] = __builtin_amdgcn_mfma_f32_16x16x32_bf16(a4, b1, acc[4][1], 0, 0, 0);
      acc[5][1] = __builtin_amdgcn_mfma_f32_16x16x32_bf16(a5, b1, acc[5][1], 0, 0, 0);
      acc[6][1] = __builtin_amdgcn_mfma_f32_16x16x32_bf16(a6, b1, acc[6][1], 0, 0, 0);
      acc[7][1] = __builtin_amdgcn_mfma_f32_16x16x32_bf16(a7, b1, acc[7][1], 0, 0, 0);
      acc[0][2] = __builtin_amdgcn_mfma_f32_16x16x32_bf16(a0, b2, acc[0][2], 0, 0, 0);
      acc[1][2] = __builtin_amdgcn_mfma_f32_16x16x32_bf16(a1, b2, acc[1][2], 0, 0, 0);
      acc[2][2] = __builtin_amdgcn_mfma_f32_16x16x32_bf16(a2, b2, acc[2][2], 0, 0, 0);
      acc[3][2] = __builtin_amdgcn_mfma_f32_16x16x32_bf16(a3, b2, acc[3][2], 0, 0, 0);
      acc[4][2] = __builtin_amdgcn_mfma_f32_16x16x32_bf16(a4, b2, acc[4][2], 0, 0, 0);
      acc[5][2] = __builtin_amdgcn_mfma_f32_16x16x32_bf16(a5, b2, acc[5][2], 0, 0, 0);
      acc[6][2] = __builtin_amdgcn_mfma_f32_16x16x32_bf16(a6, b2, acc[6][2], 0, 0, 0);
      acc[7][2] = __builtin_amdgcn_mfma_f32_16x16x32_bf16(a7, b2, acc[7][2], 0, 0, 0);
      acc[0][3] = __builtin_amdgcn_mfma_f32_16x16x32_bf16(a0, b3, acc[0][3], 0, 0, 0);
      acc[1][3] = __builtin_amdgcn_mfma_f32_16x16x32_bf16(a1, b3, acc[1][3], 0, 0, 0);
      acc[2][3] = __builtin_amdgcn_mfma_f32_16x16x32_bf16(a2, b3, acc[2][3], 0, 0, 0);
      acc[3][3] = __builtin_amdgcn_mfma_f32_16x16x32_bf16(a3, b3, acc[3][3], 0, 0, 0);
      acc[4][3] = __builtin_amdgcn_mfma_f32_16x16x32_bf16(a4, b3, acc[4][3], 0, 0, 0);
      acc[5][3] = __builtin_amdgcn_mfma_f32_16x16x32_bf16(a5, b3, acc[5][3], 0, 0, 0);
      acc[6][3] = __builtin_amdgcn_mfma_f32_16x16x32_bf16(a6, b3, acc[6][3], 0, 0, 0);
      acc[7][3] = __builtin_amdgcn_mfma_f32_16x16x32_bf16(a7, b3, acc[7][3], 0, 0, 0);
      __builtin_amdgcn_s_setprio(0);

      // staged chunk landed (my slices); barrier publishes collectively
      asm volatile("s_waitcnt vmcnt(0)" ::: "memory");
      __builtin_amdgcn_s_barrier();
      asm volatile("" ::: "memory");
    }

    // fold view into running max (packed f16)
    #pragma unroll
    for (int m = 0; m < 8; ++m)
      #pragma unroll
      for (int n = 0; n < 4; ++n) {
        f16x2 lo = __builtin_amdgcn_cvt_pkrtz(acc[m][n][0], acc[m][n][1]);
        f16x2 hi = __builtin_amdgcn_cvt_pkrtz(acc[m][n][2], acc[m][n][3]);
        om[m][n][0] = __builtin_elementwise_max(om[m][n][0], lo);
        om[m][n][1] = __builtin_elementwise_max(om[m][n][1], hi);
      }
  }

  // epilogue: unpack f16 -> f32 and store
  const int rbase = ib * 256 + wm * 128;
  const int cbase = cb * 128 + wn * 64;
  #pragma unroll
  for (int m = 0; m < 8; ++m)
    #pragma unroll
    for (int h = 0; h < 2; ++h)
      #pragma unroll
      for (int e = 0; e < 2; ++e) {
        size_t ro = (size_t)(rbase + m * 16 + lu * 4 + h * 2 + e) * NC + cbase + lrow;
        #pragma unroll
        for (int n = 0; n < 4; ++n)
          out[ro + n * 16] = (float)om[m][n][h][e];
      }
}

// ---------------- fallback (no-ws path) ------------------------------------
__global__ __launch_bounds__(512, 1)
void mvm_fallback(const float* __restrict__ imgs, const float* __restrict__ caps,
                  float* __restrict__ out)
{
  __shared__ __align__(16) char ldsB[128 * 512];
  __shared__ __align__(16) char ldsA[2][256 * 128];

  const int tid  = threadIdx.x;
  const int lane = tid & 63;
  const int wid  = tid >> 6;
  const int wr   = wid >> 1;
  const int wc   = wid & 1;
  const int i0   = blockIdx.y * 256;
  const int c0   = blockIdx.x * 128;

  #pragma unroll
  for (int it = 0; it < 8; ++it) {
    int c    = tid + it * 512;
    int row  = c >> 5;
    int colb = (c & 31) * 16;
    const float* p = caps + (size_t)(c0 + row) * DD + (c & 31) * 8;
    float4 a = *(const float4*)p;
    float4 b = *(const float4*)(p + 4);
    uint4 v;
    v.x = pkbf(a.x, a.y); v.y = pkbf(a.z, a.w);
    v.z = pkbf(b.x, b.y); v.w = pkbf(b.z, b.w);
    *(uint4*)(ldsB + row * 512 + (colb ^ ((row & 7) << 4))) = v;
  }
  #pragma unroll
  for (int it = 0; it < 4; ++it) {
    int c    = tid + it * 512;
    int row  = c >> 3;
    int colb = (c & 7) * 16;
    const float* p = imgs + ((size_t)(i0 + row) * RV + 0) * DD + (c & 7) * 8;
    float4 a = *(const float4*)p;
    float4 b = *(const float4*)(p + 4);
    uint4 v;
    v.x = pkbf(a.x, a.y); v.y = pkbf(a.z, a.w);
    v.z = pkbf(b.x, b.y); v.w = pkbf(b.z, b.w);
    *(uint4*)(ldsA[0] + row * 128 + (colb ^ ((row & 7) << 4))) = v;
  }
  __syncthreads();

  f32x4 omax[4][4];
  #pragma unroll
  for (int m = 0; m < 4; ++m)
    #pragma unroll
    for (int n = 0; n < 4; ++n)
      #pragma unroll
      for (int j = 0; j < 4; ++j)
        omax[m][n][j] = -3.4e38f;

  f32x4 acc[4][4];
  int cur = 0;
  const int lrow = lane & 15;
  const int lkb  = (lane >> 4) * 16;

  for (int ch = 0; ch < RV * 4; ++ch) {
    const int kc = ch & 3;
    if (kc == 0) {
      #pragma unroll
      for (int m = 0; m < 4; ++m)
        #pragma unroll
        for (int n = 0; n < 4; ++n)
          acc[m][n] = (f32x4){0.f, 0.f, 0.f, 0.f};
    }
    const int  chn  = ch + 1;
    const bool hasn = (chn < RV * 4);
    float4 pf[8];
    if (hasn) {
      const int rn = chn >> 2;
      const int kn = (chn & 3) * 64;
      #pragma unroll
      for (int it = 0; it < 4; ++it) {
        int c   = tid + it * 512;
        int row = c >> 3;
        const float* p = imgs + ((size_t)(i0 + row) * RV + rn) * DD + kn + (c & 7) * 8;
        pf[2 * it]     = *(const float4*)p;
        pf[2 * it + 1] = *(const float4*)(p + 4);
      }
    }
    #pragma unroll
    for (int ks = 0; ks < 2; ++ks) {
      bf16x8 af[4], bfr[4];
      #pragma unroll
      for (int m = 0; m < 4; ++m) {
        int row = wr * 64 + m * 16 + lrow;
        af[m] = *(const bf16x8*)(ldsA[cur] + row * 128 + ((ks * 64 + lkb) ^ ((row & 7) << 4)));
      }
      #pragma unroll
      for (int n = 0; n < 4; ++n) {
        int row = wc * 64 + n * 16 + lrow;
        bfr[n] = *(const bf16x8*)(ldsB + row * 512 + (((ch & 3) * 128 + ks * 64 + lkb) ^ ((row & 7) << 4)));
      }
      #pragma unroll
      for (int m = 0; m < 4; ++m)
        #pragma unroll
        for (int n = 0; n < 4; ++n)
          acc[m][n] = __builtin_amdgcn_mfma_f32_16x16x32_bf16(af[m], bfr[n], acc[m][n], 0, 0, 0);
    }
    if (hasn) {
      #pragma unroll
      for (int it = 0; it < 4; ++it) {
        int c    = tid + it * 512;
        int row  = c >> 3;
        int colb = (c & 7) * 16;
        uint4 v;
        v.x = pkbf(pf[2 * it].x,     pf[2 * it].y);
        v.y = pkbf(pf[2 * it].z,     pf[2 * it].w);
        v.z = pkbf(pf[2 * it + 1].x, pf[2 * it + 1].y);
        v.w = pkbf(pf[2 * it + 1].z, pf[2 * it + 1].w);
        *(uint4*)(ldsA[cur ^ 1] + row * 128 + (colb ^ ((row & 7) << 4))) = v;
      }
    }
    __syncthreads();
    cur ^= 1;
    if (kc == 3) {
      #pragma unroll
      for (int m = 0; m < 4; ++m)
        #pragma unroll
        for (int n = 0; n < 4; ++n)
          #pragma unroll
          for (int j = 0; j < 4; ++j)
            omax[m][n][j] = fmaxf(omax[m][n][j], acc[m][n][j]);
    }
  }

  const int rbase = i0 + wr * 64;
  const int cbase = c0 + wc * 64;
  const int lr4   = (lane >> 4) * 4;
  const int lc    = lane & 15;
  #pragma unroll
  for (int m = 0; m < 4; ++m)
    #pragma unroll
    for (int j = 0; j < 4; ++j) {
      size_t ro = (size_t)(rbase + m * 16 + lr4 + j) * NC;
      #pragma unroll
      for (int n = 0; n < 4; ++n)
        out[ro + cbase + n * 16 + lc] = omax[m][n][j];
    }
}

extern "C" void kernel_launch(void* const* d_in, const int* in_sizes, int n_in,
                              void* d_out, int out_size, void* d_ws, size_t ws_size,
                              hipStream_t stream) {
  const float* imgs = (const float*)d_in[0];
  const float* caps = (const float*)d_in[1];
  float* out = (float*)d_out;

  if (ws_size >= WS_NEEDED) {
    char* ws = (char*)d_ws;
    conv_imgs<<<7168, 256, 0, stream>>>(imgs, (uint4*)ws);
    conv_caps<<<1024, 256, 0, stream>>>(caps, (uint4*)(ws + CAPS_WS_OFF));
    mvm_mfma<<<2048, 256, 0, stream>>>((const char*)ws, (const char*)(ws + CAPS_WS_OFF), out);
  } else {
    dim3 grid(NC / 128, NI / 256);
    mvm_fallback<<<grid, 512, 0, stream>>>(imgs, caps, out);
  }
}

// Round 11
// 264.310 us; speedup vs baseline: 3.2548x; 1.2805x over previous
//
#include <hip/hip_runtime.h>
#include <hip/hip_bf16.h>
#include <cstdint>
#include <cstddef>

#define NI 8192
#define NC 8192
#define RV 7
#define DD 256

typedef __bf16  bf16x8 __attribute__((ext_vector_type(8)));
typedef float   f32x4  __attribute__((ext_vector_type(4)));
typedef __fp16  f16x2  __attribute__((ext_vector_type(2)));

// ws layout:
//   imgs: per img-block ib (32) x chunk t=r*8+j (56): [4 u][256 row] x 16B = 16KB
//   caps: per cap-block cb (64): [8 j][4 u][128 row] x 16B = 64KB
#define IMGS_WS_BYTES (32u * 56u * 16384u)   /* 29,360,128 */
#define CAPS_WS_OFF   IMGS_WS_BYTES
#define CAPS_WS_BYTES (64u * 65536u)         /* 4,194,304 */
#define WS_NEEDED     ((size_t)(IMGS_WS_BYTES + CAPS_WS_BYTES))

static __device__ __forceinline__ unsigned pkbf(float x, float y) {
  unsigned a = __float_as_uint(x) + 0x8000u;
  unsigned b = __float_as_uint(y) + 0x8000u;
  return __builtin_amdgcn_perm(b, a, 0x07060302u);
}

static __device__ __forceinline__ void gload16(const void* g, void* l) {
  __builtin_amdgcn_global_load_lds(
      (const __attribute__((address_space(1))) void*)g,
      (__attribute__((address_space(3))) void*)l, 16, 0, 0);
}

// ---------------- conversion pre-passes (f32 -> bf16, tile-image layout) ---
__global__ __launch_bounds__(256)
void conv_imgs(const float* __restrict__ imgs, uint4* __restrict__ ws) {
  unsigned T = blockIdx.x * 256u + threadIdx.x;   // 0..1,835,007
  unsigned img = T / 224u;                        // 8192 imgs x 224 units
  unsigned rem = T - img * 224u;
  unsigned r  = rem >> 5;                         // view 0..6
  unsigned ju = rem & 31u;                        // k-unit 0..31 (k = ju*8)
  const float* s = imgs + ((size_t)img * RV + r) * DD + ju * 8u;
  float4 a = *(const float4*)s;
  float4 b = *(const float4*)(s + 4);
  uint4 v = { pkbf(a.x, a.y), pkbf(a.z, a.w), pkbf(b.x, b.y), pkbf(b.z, b.w) };
  unsigned ib = img >> 8, lrow = img & 255u;
  unsigned j = ju >> 2, u = ju & 3u;
  unsigned t = r * 8u + j;
  unsigned byteoff = (ib * 56u + t) * 16384u + u * 4096u + lrow * 16u;
  ws[byteoff >> 4] = v;
}

__global__ __launch_bounds__(256)
void conv_caps(const float* __restrict__ caps, uint4* __restrict__ ws) {
  unsigned T = blockIdx.x * 256u + threadIdx.x;   // 0..262,143
  unsigned gr = T >> 5;                           // cap row 0..8191
  unsigned ju = T & 31u;                          // k-unit 0..31
  const float* s = caps + (size_t)gr * DD + ju * 8u;
  float4 a = *(const float4*)s;
  float4 b = *(const float4*)(s + 4);
  uint4 v = { pkbf(a.x, a.y), pkbf(a.z, a.w), pkbf(b.x, b.y), pkbf(b.z, b.w) };
  unsigned cb = gr >> 7, row = gr & 127u;         // 64 panels x 128 rows
  unsigned j = ju >> 2, u = ju & 3u;
  unsigned byteoff = cb * 65536u + j * 8192u + u * 2048u + row * 16u;
  ws[byteoff >> 4] = v;
}

// ---------------- main GEMM+max kernel ------------------------------------
// block tile 256 imgs x 128 caps; 8 waves (4m x 2n), wave tile 64x64.
// B resident 64KB; A chunks 16KB x 4 buffers (128KB LDS total, 1 block/CU).
// Intra-wave fragment double-buffer (T3 mechanism): chunk t+1's ds_reads are
// issued BEFORE chunk t's MFMA cluster, so the LDS port fills during MFMA
// (compiler emits counted lgkmcnt). Staging runs 3 chunks ahead with a
// per-chunk COUNTED vmcnt(2) (never 0): at end of chunk t, stage(t+2) is
// drained and published by the barrier (one chunk EARLY), which is what
// legalizes reading chunk t+1's fragments during chunk t.
// Buffers at chunk t: (t+1)&3 read, (t+2)&3 draining, (t+3)&3 in flight,
// t&3 free. WAR on a buffer is separated by >=2 barriers.
#define LOAD_SET(P, BUFN, JN)                                   \
  P##a0 = *(const bf16x8*)(aF + (BUFN)*16384 + 0*256);          \
  P##a1 = *(const bf16x8*)(aF + (BUFN)*16384 + 1*256);          \
  P##a2 = *(const bf16x8*)(aF + (BUFN)*16384 + 2*256);          \
  P##a3 = *(const bf16x8*)(aF + (BUFN)*16384 + 3*256);          \
  P##b0 = *(const bf16x8*)(bF + (JN)*8192 + 0*256);             \
  P##b1 = *(const bf16x8*)(bF + (JN)*8192 + 1*256);             \
  P##b2 = *(const bf16x8*)(bF + (JN)*8192 + 2*256);             \
  P##b3 = *(const bf16x8*)(bF + (JN)*8192 + 3*256);

#define MFMA_SET(P)                                                              \
  acc[0][0] = __builtin_amdgcn_mfma_f32_16x16x32_bf16(P##a0, P##b0, acc[0][0], 0, 0, 0); \
  acc[1][0] = __builtin_amdgcn_mfma_f32_16x16x32_bf16(P##a1, P##b0, acc[1][0], 0, 0, 0); \
  acc[2][0] = __builtin_amdgcn_mfma_f32_16x16x32_bf16(P##a2, P##b0, acc[2][0], 0, 0, 0); \
  acc[3][0] = __builtin_amdgcn_mfma_f32_16x16x32_bf16(P##a3, P##b0, acc[3][0], 0, 0, 0); \
  acc[0][1] = __builtin_amdgcn_mfma_f32_16x16x32_bf16(P##a0, P##b1, acc[0][1], 0, 0, 0); \
  acc[1][1] = __builtin_amdgcn_mfma_f32_16x16x32_bf16(P##a1, P##b1, acc[1][1], 0, 0, 0); \
  acc[2][1] = __builtin_amdgcn_mfma_f32_16x16x32_bf16(P##a2, P##b1, acc[2][1], 0, 0, 0); \
  acc[3][1] = __builtin_amdgcn_mfma_f32_16x16x32_bf16(P##a3, P##b1, acc[3][1], 0, 0, 0); \
  acc[0][2] = __builtin_amdgcn_mfma_f32_16x16x32_bf16(P##a0, P##b2, acc[0][2], 0, 0, 0); \
  acc[1][2] = __builtin_amdgcn_mfma_f32_16x16x32_bf16(P##a1, P##b2, acc[1][2], 0, 0, 0); \
  acc[2][2] = __builtin_amdgcn_mfma_f32_16x16x32_bf16(P##a2, P##b2, acc[2][2], 0, 0, 0); \
  acc[3][2] = __builtin_amdgcn_mfma_f32_16x16x32_bf16(P##a3, P##b2, acc[3][2], 0, 0, 0); \
  acc[0][3] = __builtin_amdgcn_mfma_f32_16x16x32_bf16(P##a0, P##b3, acc[0][3], 0, 0, 0); \
  acc[1][3] = __builtin_amdgcn_mfma_f32_16x16x32_bf16(P##a1, P##b3, acc[1][3], 0, 0, 0); \
  acc[2][3] = __builtin_amdgcn_mfma_f32_16x16x32_bf16(P##a2, P##b3, acc[2][3], 0, 0, 0); \
  acc[3][3] = __builtin_amdgcn_mfma_f32_16x16x32_bf16(P##a3, P##b3, acc[3][3], 0, 0, 0);

#define CHUNK(CUR, NXT, BUFN, JN)                                        \
  LOAD_SET(NXT, BUFN, JN)                                                \
  gload16(stp,        ldsA + (((BUFN)+2)&3)*16384 + wid*1024);           \
  gload16(stp + 8192, ldsA + (((BUFN)+2)&3)*16384 + 8192 + wid*1024);    \
  stp += 16384;                                                          \
  __builtin_amdgcn_s_setprio(1);                                         \
  MFMA_SET(CUR)                                                          \
  __builtin_amdgcn_s_setprio(0);                                         \
  asm volatile("s_waitcnt vmcnt(2)" ::: "memory");                       \
  __builtin_amdgcn_s_barrier();                                          \
  asm volatile("" ::: "memory");

__global__ __launch_bounds__(512, 2)
void mvm_mfma(const char* __restrict__ wi, const char* __restrict__ wcap,
              float* __restrict__ out)
{
  __shared__ __align__(1024) char lds[131072];
  char* const ldsA = lds;            // 4 x 16KB imgs chunk buffers
  char* const ldsB = lds + 65536;    // 64KB caps (full K, [8 j][4 u][128 row])

  const int tid  = threadIdx.x;
  const int lane = tid & 63;
  const int wid  = tid >> 6;   // 0..7
  const int wm   = wid >> 1;   // 0..3 : m-strip of 64
  const int wn   = wid & 1;    // 0..1 : n-strip of 64

  const int bid = (int)blockIdx.x;                 // 2048 blocks
  const int swz = (bid & 7) * 256 + (bid >> 3);    // bijective XCD swizzle
  const int ib  = swz >> 6;    // 0..31 : A panel shared by 64 consecutive swz
  const int cb  = swz & 63;    // 0..63

  const char* abase = wi   + (size_t)ib * (56u * 16384u);
  const char* bbase = wcap + (size_t)cb * 65536u;

  // prologue: B (8 gloads) + A chunks 0,1,2 (2 gloads each)
  #pragma unroll
  for (int l = 0; l < 8; ++l)
    gload16(bbase + l * 8192 + tid * 16, ldsB + l * 8192 + wid * 1024);
  #pragma unroll
  for (int c = 0; c < 3; ++c) {
    gload16(abase + c * 16384 + tid * 16,        ldsA + c * 16384 + wid * 1024);
    gload16(abase + c * 16384 + 8192 + tid * 16, ldsA + c * 16384 + 8192 + wid * 1024);
  }
  asm volatile("s_waitcnt vmcnt(2)" ::: "memory");  // B + chunks 0,1 drained
  __builtin_amdgcn_s_barrier();
  asm volatile("" ::: "memory");

  const int lrow = lane & 15;
  const int lu   = lane >> 4;
  const char* const aF = ldsA + lu * 4096 + (wm * 64 + lrow) * 16;
  const char* const bF = ldsB + lu * 2048 + (wn * 64 + lrow) * 16;
  const char* stp = abase + 3 * 16384 + tid * 16;   // next chunk to stage = 3

  bf16x8 s0a0, s0a1, s0a2, s0a3, s0b0, s0b1, s0b2, s0b3;
  bf16x8 s1a0, s1a1, s1a2, s1a3, s1b0, s1b1, s1b2, s1b3;
  LOAD_SET(s0, 0, 0)   // f_cur for chunk 0

  f16x2 om[4][4][2];
  #pragma unroll
  for (int m = 0; m < 4; ++m)
    #pragma unroll
    for (int n = 0; n < 4; ++n)
      #pragma unroll
      for (int h = 0; h < 2; ++h)
        om[m][n][h] = (f16x2){(__fp16)-65504.f, (__fp16)-65504.f};

  f32x4 acc[4][4];

  #pragma unroll 1
  for (int r = 0; r < RV; ++r) {
    #pragma unroll
    for (int m = 0; m < 4; ++m)
      #pragma unroll
      for (int n = 0; n < 4; ++n)
        acc[m][n] = (f32x4){0.f, 0.f, 0.f, 0.f};

    // 8 chunks; f_next(t+1) reads issued BEFORE MFMA(t); buffers mod 4.
    CHUNK(s0, s1, 1, 1)   // j=0
    CHUNK(s1, s0, 2, 2)   // j=1
    CHUNK(s0, s1, 3, 3)   // j=2
    CHUNK(s1, s0, 0, 4)   // j=3
    CHUNK(s0, s1, 1, 5)   // j=4
    CHUNK(s1, s0, 2, 6)   // j=5
    CHUNK(s0, s1, 3, 7)   // j=6
    CHUNK(s1, s0, 0, 0)   // j=7 -> loads next view's chunk into s0
    // (tail overruns stage reads into the caps region of ws: in-bounds,
    //  target buffers never consumed; final CHUNK's s0 load is garbage only
    //  after the last view, where it is never used)

    #pragma unroll
    for (int m = 0; m < 4; ++m)
      #pragma unroll
      for (int n = 0; n < 4; ++n) {
        f16x2 lo = __builtin_amdgcn_cvt_pkrtz(acc[m][n][0], acc[m][n][1]);
        f16x2 hi = __builtin_amdgcn_cvt_pkrtz(acc[m][n][2], acc[m][n][3]);
        om[m][n][0] = __builtin_elementwise_max(om[m][n][0], lo);
        om[m][n][1] = __builtin_elementwise_max(om[m][n][1], hi);
      }
  }

  // epilogue: unpack f16 -> f32 and store
  const int rbase = ib * 256 + wm * 64;
  const int cbase = cb * 128 + wn * 64;
  #pragma unroll
  for (int m = 0; m < 4; ++m)
    #pragma unroll
    for (int h = 0; h < 2; ++h)
      #pragma unroll
      for (int e = 0; e < 2; ++e) {
        size_t ro = (size_t)(rbase + m * 16 + lu * 4 + h * 2 + e) * NC + cbase + lrow;
        #pragma unroll
        for (int n = 0; n < 4; ++n)
          out[ro + n * 16] = (float)om[m][n][h][e];
      }
}

// ---------------- fallback (no-ws path) ------------------------------------
__global__ __launch_bounds__(512, 1)
void mvm_fallback(const float* __restrict__ imgs, const float* __restrict__ caps,
                  float* __restrict__ out)
{
  __shared__ __align__(16) char ldsB[128 * 512];
  __shared__ __align__(16) char ldsA[2][256 * 128];

  const int tid  = threadIdx.x;
  const int lane = tid & 63;
  const int wid  = tid >> 6;
  const int wr   = wid >> 1;
  const int wc   = wid & 1;
  const int i0   = blockIdx.y * 256;
  const int c0   = blockIdx.x * 128;

  #pragma unroll
  for (int it = 0; it < 8; ++it) {
    int c    = tid + it * 512;
    int row  = c >> 5;
    int colb = (c & 31) * 16;
    const float* p = caps + (size_t)(c0 + row) * DD + (c & 31) * 8;
    float4 a = *(const float4*)p;
    float4 b = *(const float4*)(p + 4);
    uint4 v;
    v.x = pkbf(a.x, a.y); v.y = pkbf(a.z, a.w);
    v.z = pkbf(b.x, b.y); v.w = pkbf(b.z, b.w);
    *(uint4*)(ldsB + row * 512 + (colb ^ ((row & 7) << 4))) = v;
  }
  #pragma unroll
  for (int it = 0; it < 4; ++it) {
    int c    = tid + it * 512;
    int row  = c >> 3;
    int colb = (c & 7) * 16;
    const float* p = imgs + ((size_t)(i0 + row) * RV + 0) * DD + (c & 7) * 8;
    float4 a = *(const float4*)p;
    float4 b = *(const float4*)(p + 4);
    uint4 v;
    v.x = pkbf(a.x, a.y); v.y = pkbf(a.z, a.w);
    v.z = pkbf(b.x, b.y); v.w = pkbf(b.z, b.w);
    *(uint4*)(ldsA[0] + row * 128 + (colb ^ ((row & 7) << 4))) = v;
  }
  __syncthreads();

  f32x4 omax[4][4];
  #pragma unroll
  for (int m = 0; m < 4; ++m)
    #pragma unroll
    for (int n = 0; n < 4; ++n)
      #pragma unroll
      for (int j = 0; j < 4; ++j)
        omax[m][n][j] = -3.4e38f;

  f32x4 acc[4][4];
  int cur = 0;
  const int lrow = lane & 15;
  const int lkb  = (lane >> 4) * 16;

  for (int ch = 0; ch < RV * 4; ++ch) {
    const int kc = ch & 3;
    if (kc == 0) {
      #pragma unroll
      for (int m = 0; m < 4; ++m)
        #pragma unroll
        for (int n = 0; n < 4; ++n)
          acc[m][n] = (f32x4){0.f, 0.f, 0.f, 0.f};
    }
    const int  chn  = ch + 1;
    const bool hasn = (chn < RV * 4);
    float4 pf[8];
    if (hasn) {
      const int rn = chn >> 2;
      const int kn = (chn & 3) * 64;
      #pragma unroll
      for (int it = 0; it < 4; ++it) {
        int c   = tid + it * 512;
        int row = c >> 3;
        const float* p = imgs + ((size_t)(i0 + row) * RV + rn) * DD + kn + (c & 7) * 8;
        pf[2 * it]     = *(const float4*)p;
        pf[2 * it + 1] = *(const float4*)(p + 4);
      }
    }
    #pragma unroll
    for (int ks = 0; ks < 2; ++ks) {
      bf16x8 af[4], bfr[4];
      #pragma unroll
      for (int m = 0; m < 4; ++m) {
        int row = wr * 64 + m * 16 + lrow;
        af[m] = *(const bf16x8*)(ldsA[cur] + row * 128 + ((ks * 64 + lkb) ^ ((row & 7) << 4)));
      }
      #pragma unroll
      for (int n = 0; n < 4; ++n) {
        int row = wc * 64 + n * 16 + lrow;
        bfr[n] = *(const bf16x8*)(ldsB + row * 512 + (((ch & 3) * 128 + ks * 64 + lkb) ^ ((row & 7) << 4)));
      }
      #pragma unroll
      for (int m = 0; m < 4; ++m)
        #pragma unroll
        for (int n = 0; n < 4; ++n)
          acc[m][n] = __builtin_amdgcn_mfma_f32_16x16x32_bf16(af[m], bfr[n], acc[m][n], 0, 0, 0);
    }
    if (hasn) {
      #pragma unroll
      for (int it = 0; it < 4; ++it) {
        int c    = tid + it * 512;
        int row  = c >> 3;
        int colb = (c & 7) * 16;
        uint4 v;
        v.x = pkbf(pf[2 * it].x,     pf[2 * it].y);
        v.y = pkbf(pf[2 * it].z,     pf[2 * it].w);
        v.z = pkbf(pf[2 * it + 1].x, pf[2 * it + 1].y);
        v.w = pkbf(pf[2 * it + 1].z, pf[2 * it + 1].w);
        *(uint4*)(ldsA[cur ^ 1] + row * 128 + (colb ^ ((row & 7) << 4))) = v;
      }
    }
    __syncthreads();
    cur ^= 1;
    if (kc == 3) {
      #pragma unroll
      for (int m = 0; m < 4; ++m)
        #pragma unroll
        for (int n = 0; n < 4; ++n)
          #pragma unroll
          for (int j = 0; j < 4; ++j)
            omax[m][n][j] = fmaxf(omax[m][n][j], acc[m][n][j]);
    }
  }

  const int rbase = i0 + wr * 64;
  const int cbase = c0 + wc * 64;
  const int lr4   = (lane >> 4) * 4;
  const int lc    = lane & 15;
  #pragma unroll
  for (int m = 0; m < 4; ++m)
    #pragma unroll
    for (int j = 0; j < 4; ++j) {
      size_t ro = (size_t)(rbase + m * 16 + lr4 + j) * NC;
      #pragma unroll
      for (int n = 0; n < 4; ++n)
        out[ro + cbase + n * 16 + lc] = omax[m][n][j];
    }
}

extern "C" void kernel_launch(void* const* d_in, const int* in_sizes, int n_in,
                              void* d_out, int out_size, void* d_ws, size_t ws_size,
                              hipStream_t stream) {
  const float* imgs = (const float*)d_in[0];
  const float* caps = (const float*)d_in[1];
  float* out = (float*)d_out;

  if (ws_size >= WS_NEEDED) {
    char* ws = (char*)d_ws;
    conv_imgs<<<7168, 256, 0, stream>>>(imgs, (uint4*)ws);
    conv_caps<<<1024, 256, 0, stream>>>(caps, (uint4*)(ws + CAPS_WS_OFF));
    mvm_mfma<<<2048, 512, 0, stream>>>((const char*)ws, (const char*)(ws + CAPS_WS_OFF), out);
  } else {
    dim3 grid(NC / 128, NI / 256);
    mvm_fallback<<<grid, 512, 0, stream>>>(imgs, caps, out);
  }
}